// Round 14
// baseline (146.422 us; speedup 1.0000x reference)
//
#include <hip/hip_runtime.h>

#define T_LEN  1048576
#define NROWS  32
#define NTAPS  128
#define N2     32
#define BLOCK  256
#define SEG    4096           /* outputs per block (4 waves x 1024) */
#define SEGS_PER_ROW 256
#define NCH    11             /* K chunks of 16: k = m + 129 - 16c - s */
#define W_OUT  1024           /* outputs per wave */
#define W_Q4   292            /* float4 loads per wave (1168 elems) */
#define XH_W_BYTES 2432       /* 152 padded 16B chunks (146 used) */
#define EPI_W_BYTES 4096
#define WAVE_BYTES (XH_W_BYTES + EPI_W_BYTES)   /* 6528 */
#define SMEM_BYTES (4 * WAVE_BYTES)             /* 26112 */

/* two-tile variant */
#define W2_OUT 2048
#define W2_Q4  548            /* float4 loads per wave (2192 elems) */
#define XH2_W_BYTES 4416      /* 276 padded 16B chunks (274 used) */
#define WAVE2_BYTES (XH2_W_BYTES + EPI_W_BYTES) /* 8512 */
#define SMEM2_BYTES (4 * WAVE2_BYTES)           /* 34048 */

typedef __attribute__((ext_vector_type(8)))  _Float16 half8;
typedef __attribute__((ext_vector_type(2)))  __fp16   fp16x2;
typedef __attribute__((ext_vector_type(16))) float    f32x16;
typedef __attribute__((ext_vector_type(4)))  float    f32x4;

__device__ __forceinline__ int swz16(int q) { return q ^ ((q >> 3) & 7); }

// ---- kernel 1: impulse response h[0..127] (+D at 0); fp16 Toeplitz A-frags ----
__global__ __launch_bounds__(NTAPS) void ssm_taps(
    const float* __restrict__ w_real, const float* __restrict__ w_imag,
    const float* __restrict__ log_dt,
    const float* __restrict__ C_real, const float* __restrict__ C_imag,
    const float* __restrict__ B_real, const float* __restrict__ B_imag,
    const float* __restrict__ Dp, float* __restrict__ ws) {
  __shared__ float hsh[NTAPS];
  const int k = threadIdx.x;
  const float dt = expf(log_dt[0]);
  const float kf = (float)k;
  float acc = 0.f;
  for (int n = 0; n < N2; ++n) {
    const float a  = dt * w_real[n];
    const float b  = dt * w_imag[n];
    const float cr = C_real[n], ci = C_imag[n];
    const float br = B_real[n], bi = B_imag[n];
    const float coef_r = cr * br - ci * bi;
    const float coef_i = cr * bi + ci * br;
    const float e = expf(a * kf);
    float s, c;
    sincosf(b * kf, &s, &c);
    acc += e * (coef_r * c - coef_i * s);
  }
  if (k == 0) acc += Dp[0];
  ws[k]  = acc;
  hsh[k] = acc;
  __syncthreads();
  if (k < 64) {
    _Float16* AH = (_Float16*)(ws + NTAPS);
    const int m = k & 31, g = k >> 5;
    for (int c = 0; c < NCH; ++c)
      for (int i = 0; i < 8; ++i) {
        const int idx = m + 129 - 16 * c - 8 * g - i;
        const float v = (idx >= 0 && idx < NTAPS) ? hsh[idx] : 0.f;
        AH[(c * 64 + k) * 8 + i] = (_Float16)v;
      }
  }
}

// ---- probe: pure streaming, same grid & addresses, 2 passes (512 MB) ----
__global__ __launch_bounds__(BLOCK) void ssm_copy(
    const float* __restrict__ x, const float* __restrict__ ws,
    float* __restrict__ out) {
  const float h0 = ws[0];
  const int row = blockIdx.x >> 8, jb = blockIdx.x & 255;
  const f32x4* __restrict__ xi = (const f32x4*)(x + (size_t)row * T_LEN + jb * SEG);
  f32x4* __restrict__ oi = (f32x4*)(out + (size_t)row * T_LEN + jb * SEG);
#pragma unroll
  for (int j = 0; j < 4; ++j)
    oi[threadIdx.x + 256 * j] = xi[threadIdx.x + 256 * j] * h0;
  asm volatile("" ::: "memory");             // force a genuine second pass
#pragma unroll
  for (int j = 0; j < 4; ++j)
    oi[threadIdx.x + 256 * j] = xi[threadIdx.x + 256 * j] * h0;
}

// ---- candidate: two 32x32 tiles per wave (2048 outputs), barrier-free ----
__global__ __launch_bounds__(BLOCK, 4) void ssm_conv2(
    const float* __restrict__ x, const float* __restrict__ ws,
    float* __restrict__ out) {
  __shared__ __align__(16) unsigned char smem[SMEM2_BYTES];
  const int tid  = threadIdx.x;
  const int lane = tid & 63;
  const int wid  = tid >> 6;
  const int p    = lane & 31, g = lane >> 5;
  const int row  = blockIdx.x >> 7;          // 128 blocks per row
  const int jb   = blockIdx.x & 127;
  const int W0   = jb * (4 * W2_OUT) + wid * W2_OUT;
  const float* __restrict__ xrow = x + (size_t)row * T_LEN;

  char*  xw   = (char*)smem + wid * WAVE2_BYTES;
  float* ebuf = (float*)(xw + XH2_W_BYTES);

  half8 A[NCH];
  const half8* __restrict__ wsA = (const half8*)(ws + NTAPS);
#pragma unroll
  for (int c = 0; c < NCH; ++c) A[c] = wsA[c * 64 + lane];

#pragma unroll
  for (int j = 0; j < 9; ++j) {
    const int q4 = lane + 64 * j;
    if (q4 < W2_Q4) {
      int gfi = W0 - 256 + 4 * q4;
      gfi = gfi < 0 ? 0 : gfi;
      const float4 f = *(const float4*)(xrow + gfi);
      const fp16x2 a = __builtin_amdgcn_cvt_pkrtz(f.x, f.y);
      const fp16x2 b = __builtin_amdgcn_cvt_pkrtz(f.z, f.w);
      uint2 w;
      w.x = __builtin_bit_cast(unsigned, a);
      w.y = __builtin_bit_cast(unsigned, b);
      *(uint2*)(xw + swz16(q4 >> 1) * 16 + (q4 & 1) * 8) = w;
    }
  }

  const int qb = 4 * p + g;
  f32x16 acc0 = {}, acc1 = {};
#pragma unroll
  for (int c = 0; c < NCH; ++c) {
    const half8 B0 = *(const half8*)(xw + swz16(qb + 2 * c) * 16);
    acc0 = __builtin_amdgcn_mfma_f32_32x32x16_f16(A[c], B0, acc0, 0, 0, 0);
    const half8 B1 = *(const half8*)(xw + swz16(qb + 128 + 2 * c) * 16);
    acc1 = __builtin_amdgcn_mfma_f32_32x32x16_f16(A[c], B1, acc1, 0, 0, 0);
  }

#pragma unroll
  for (int tt = 0; tt < 2; ++tt) {
    const f32x16& acc = tt ? acc1 : acc0;
#pragma unroll
    for (int k = 0; k < 4; ++k) {
      const int q = p * 8 + 2 * k + g;
      float4 v;
      v.x = acc[4 * k];     v.y = acc[4 * k + 1];
      v.z = acc[4 * k + 2]; v.w = acc[4 * k + 3];
      *(float4*)(ebuf + (q ^ (p & 7)) * 4) = v;
    }
    float* __restrict__ obase = out + (size_t)row * T_LEN + W0 + tt * 1024;
#pragma unroll
    for (int pp = 0; pp < 4; ++pp) {
      const int o  = 4 * lane + 256 * pp;
      const int pc = o >> 5;
      const int q  = pc * 8 + (lane & 7);
      const f32x4 v = *(const f32x4*)(ebuf + (q ^ (pc & 7)) * 4);
      __builtin_nontemporal_store(v, (f32x4*)(obase + o));
    }
  }
}

// ---- reference: R12 barrier-free one-tile kernel (runs LAST; exact tail) ----
__global__ __launch_bounds__(BLOCK, 4) void ssm_conv(
    const float* __restrict__ x, const float* __restrict__ ws,
    float* __restrict__ out) {
  __shared__ __align__(16) unsigned char smem[SMEM_BYTES];

  const int tid  = threadIdx.x;
  const int lane = tid & 63;
  const int wid  = tid >> 6;
  const int p    = lane & 31, g = lane >> 5;
  const int row  = blockIdx.x >> 8;
  const int jb   = blockIdx.x & 255;
  const int W0   = jb * SEG + wid * W_OUT;
  const float* __restrict__ xrow = x + (size_t)row * T_LEN;

  char*  xw   = (char*)smem + wid * WAVE_BYTES;
  float* ebuf = (float*)(xw + XH_W_BYTES);

  half8 A[NCH];
  const half8* __restrict__ wsA = (const half8*)(ws + NTAPS);
#pragma unroll
  for (int c = 0; c < NCH; ++c) A[c] = wsA[c * 64 + lane];

#pragma unroll
  for (int j = 0; j < 5; ++j) {
    const int q4 = lane + 64 * j;
    if (q4 < W_Q4) {
      int gfi = W0 - 256 + 4 * q4;
      gfi = gfi < 0 ? 0 : gfi;
      const float4 f = *(const float4*)(xrow + gfi);
      const fp16x2 a = __builtin_amdgcn_cvt_pkrtz(f.x, f.y);
      const fp16x2 b = __builtin_amdgcn_cvt_pkrtz(f.z, f.w);
      uint2 w;
      w.x = __builtin_bit_cast(unsigned, a);
      w.y = __builtin_bit_cast(unsigned, b);
      *(uint2*)(xw + swz16(q4 >> 1) * 16 + (q4 & 1) * 8) = w;
    }
  }

  const int qb = 4 * p + g;
  f32x16 acc = {};
#pragma unroll
  for (int c = 0; c < NCH; ++c) {
    const half8 B = *(const half8*)(xw + swz16(qb + 2 * c) * 16);
    acc = __builtin_amdgcn_mfma_f32_32x32x16_f16(A[c], B, acc, 0, 0, 0);
  }

#pragma unroll
  for (int k = 0; k < 4; ++k) {
    const int q = p * 8 + 2 * k + g;
    float4 v;
    v.x = acc[4 * k];     v.y = acc[4 * k + 1];
    v.z = acc[4 * k + 2]; v.w = acc[4 * k + 3];
    *(float4*)(ebuf + (q ^ (p & 7)) * 4) = v;
  }
  float* __restrict__ obase = out + (size_t)row * T_LEN + W0;
#pragma unroll
  for (int pp = 0; pp < 4; ++pp) {
    const int o  = 4 * lane + 256 * pp;
    const int pc = o >> 5;
    const int q  = pc * 8 + (lane & 7);
    const f32x4 v = *(const f32x4*)(ebuf + (q ^ (pc & 7)) * 4);
    __builtin_nontemporal_store(v, (f32x4*)(obase + o));
  }

  if (jb == 0) {
    __syncthreads();
    const float* __restrict__ h = ws;
    if (tid < 254) {
      float a = 0.f;
      if (tid < 127) {
        for (int k = tid + 1; k < NTAPS; ++k)
          a += h[k] * xrow[T_LEN + tid - k];
      } else {
        for (int k = 0; k <= tid - 127; ++k)
          a += h[k] * xrow[tid - 127 - k];
      }
      out[(size_t)row * T_LEN + tid] = a;
    }
  }
}

extern "C" void kernel_launch(void* const* d_in, const int* in_sizes, int n_in,
                              void* d_out, int out_size, void* d_ws, size_t ws_size,
                              hipStream_t stream) {
  const float* x      = (const float*)d_in[0];
  const float* w_real = (const float*)d_in[1];
  const float* w_imag = (const float*)d_in[2];
  const float* log_dt = (const float*)d_in[3];
  const float* C_real = (const float*)d_in[4];
  const float* C_imag = (const float*)d_in[5];
  const float* B_real = (const float*)d_in[6];
  const float* B_imag = (const float*)d_in[7];
  const float* Dp     = (const float*)d_in[8];
  float* out = (float*)d_out;
  float* ws  = (float*)d_ws;

  ssm_taps<<<1, NTAPS, 0, stream>>>(w_real, w_imag, log_dt,
                                    C_real, C_imag, B_real, B_imag, Dp, ws);
  // ablation probes (outputs overwritten by the final correct pass)
  ssm_copy <<<NROWS * SEGS_PER_ROW, BLOCK, 0, stream>>>(x, ws, out);
  ssm_conv2<<<NROWS * 128,          BLOCK, 0, stream>>>(x, ws, out);
  // correct final pass
  ssm_conv <<<NROWS * SEGS_PER_ROW, BLOCK, 0, stream>>>(x, ws, out);
}

// Round 15
// 62.594 us; speedup vs baseline: 2.3392x; 2.3392x over previous
//
#include <hip/hip_runtime.h>

#define T_LEN  1048576
#define NROWS  32
#define NTAPS  128
#define N2     32
#define BLOCK  256
#define NCH    11             /* K chunks of 16: k = m + 129 - 16c - s */
#define W_OUT  2048           /* outputs per wave (2 MFMA tiles) */
#define BPR    128            /* blocks per row */
#define W_Q4   548            /* float4 loads per wave (2192 elems) */
#define XH_W_BYTES 4416       /* 276 padded 16B chunks (274 used) */
#define EPI_W_BYTES 4096
#define WAVE_BYTES (XH_W_BYTES + EPI_W_BYTES)   /* 8512 */
#define SMEM_BYTES (4 * WAVE_BYTES)             /* 34048 */

typedef __attribute__((ext_vector_type(8)))  _Float16 half8;
typedef __attribute__((ext_vector_type(2)))  __fp16   fp16x2;
typedef __attribute__((ext_vector_type(16))) float    f32x16;
typedef __attribute__((ext_vector_type(4)))  float    f32x4;

__device__ __forceinline__ int swz16(int q) { return q ^ ((q >> 3) & 7); }

// ---- kernel 1: impulse response h[0..127] (+D at 0); fp16 Toeplitz A-frags ----
// A_c[m,s] = h[m + 129 - 16c - s], lane=(m=lane&31, g=lane>>5), s=8g+i
__global__ __launch_bounds__(NTAPS) void ssm_taps(
    const float* __restrict__ w_real, const float* __restrict__ w_imag,
    const float* __restrict__ log_dt,
    const float* __restrict__ C_real, const float* __restrict__ C_imag,
    const float* __restrict__ B_real, const float* __restrict__ B_imag,
    const float* __restrict__ Dp, float* __restrict__ ws) {
  __shared__ float hsh[NTAPS];
  const int k = threadIdx.x;
  const float dt = expf(log_dt[0]);
  const float kf = (float)k;
  float acc = 0.f;
  for (int n = 0; n < N2; ++n) {
    const float a  = dt * w_real[n];
    const float b  = dt * w_imag[n];
    const float cr = C_real[n], ci = C_imag[n];
    const float br = B_real[n], bi = B_imag[n];
    const float coef_r = cr * br - ci * bi;
    const float coef_i = cr * bi + ci * br;
    const float e = expf(a * kf);
    float s, c;
    sincosf(b * kf, &s, &c);
    acc += e * (coef_r * c - coef_i * s);
  }
  if (k == 0) acc += Dp[0];
  ws[k]  = acc;                              // plain h (exact tail)
  hsh[k] = acc;
  __syncthreads();
  if (k < 64) {
    _Float16* AH = (_Float16*)(ws + NTAPS);
    const int m = k & 31, g = k >> 5;
    for (int c = 0; c < NCH; ++c)
      for (int i = 0; i < 8; ++i) {
        const int idx = m + 129 - 16 * c - 8 * g - i;
        const float v = (idx >= 0 && idx < NTAPS) ? hsh[idx] : 0.f;
        AH[(c * 64 + k) * 8 + i] = (_Float16)v;   // RNE
      }
  }
}

// ---- kernel 2: barrier-free implicit-GEMM FIR, TWO 32x32 tiles per wave.
//      Wave-private stage (fp16, swizzled) -> 22 MFMA-B reads -> 2 MFMA chains
//      -> wave-private swizzled transpose epilogue -> NT coalesced stores. ----
__global__ __launch_bounds__(BLOCK, 4) void ssm_conv(
    const float* __restrict__ x, const float* __restrict__ ws,
    float* __restrict__ out) {
  __shared__ __align__(16) unsigned char smem[SMEM_BYTES];
  const int tid  = threadIdx.x;
  const int lane = tid & 63;
  const int wid  = tid >> 6;
  const int p    = lane & 31, g = lane >> 5;
  const int row  = blockIdx.x >> 7;          // 128 blocks per row
  const int jb   = blockIdx.x & 127;
  const int W0   = jb * (4 * W_OUT) + wid * W_OUT;   // wave's output base
  const float* __restrict__ xrow = x + (size_t)row * T_LEN;

  char*  xw   = (char*)smem + wid * WAVE_BYTES;      // wave-private stage
  float* ebuf = (float*)(xw + XH_W_BYTES);           // wave-private epi

  // A fragments -> VGPRs (L2-hot, coalesced dwordx4)
  half8 A[NCH];
  const half8* __restrict__ wsA = (const half8*)(ws + NTAPS);
#pragma unroll
  for (int c = 0; c < NCH; ++c) A[c] = wsA[c * 64 + lane];

  // stage wave's 2192-elem window as fp16 (staged e <-> x[W0 - 256 + e])
#pragma unroll
  for (int j = 0; j < 9; ++j) {
    const int q4 = lane + 64 * j;            // float4 index within window
    if (q4 < W_Q4) {
      int gfi = W0 - 256 + 4 * q4;           // clamp left edge (tail re-fixes)
      gfi = gfi < 0 ? 0 : gfi;
      const float4 f = *(const float4*)(xrow + gfi);
      const fp16x2 a = __builtin_amdgcn_cvt_pkrtz(f.x, f.y);
      const fp16x2 b = __builtin_amdgcn_cvt_pkrtz(f.z, f.w);
      uint2 w;
      w.x = __builtin_bit_cast(unsigned, a);
      w.y = __builtin_bit_cast(unsigned, b);
      *(uint2*)(xw + swz16(q4 >> 1) * 16 + (q4 & 1) * 8) = w;
    }
  }
  // no barrier: same-wave ds ops are in-order / lgkmcnt-tracked

  // compute: 2 tiles x 11 x { ds_read_b128 + MFMA }
  const int qb = 4 * p + g;                  // lane's fp16-chunk base
  f32x16 acc0 = {}, acc1 = {};
#pragma unroll
  for (int c = 0; c < NCH; ++c) {
    const half8 B0 = *(const half8*)(xw + swz16(qb + 2 * c) * 16);
    acc0 = __builtin_amdgcn_mfma_f32_32x32x16_f16(A[c], B0, acc0, 0, 0, 0);
    const half8 B1 = *(const half8*)(xw + swz16(qb + 128 + 2 * c) * 16);
    acc1 = __builtin_amdgcn_mfma_f32_32x32x16_f16(A[c], B1, acc1, 0, 0, 0);
  }

  // epilogue per tile: [32 pc][8 qm] float4-quad grid, XOR-swizzled ->
  // conflict-free writes AND reads; then 4 coalesced NT dwordx4 stores.
#pragma unroll
  for (int tt = 0; tt < 2; ++tt) {
    const f32x16& acc = tt ? acc1 : acc0;
#pragma unroll
    for (int k = 0; k < 4; ++k) {            // quad r=4k..4k+3: m=8k+4g+j, col p
      const int q = p * 8 + 2 * k + g;
      float4 v;
      v.x = acc[4 * k];     v.y = acc[4 * k + 1];
      v.z = acc[4 * k + 2]; v.w = acc[4 * k + 3];
      *(float4*)(ebuf + (q ^ (p & 7)) * 4) = v;
    }
    float* __restrict__ obase = out + (size_t)row * T_LEN + W0 + tt * 1024;
#pragma unroll
    for (int pp = 0; pp < 4; ++pp) {
      const int o  = 4 * lane + 256 * pp;    // outputs o..o+3 (o = 32*pc + m)
      const int pc = o >> 5;
      const int q  = pc * 8 + (lane & 7);
      const f32x4 v = *(const f32x4*)(ebuf + (q ^ (pc & 7)) * 4);
      __builtin_nontemporal_store(v, (f32x4*)(obase + o));
    }
  }

  // merged exact fp32 tail: first block of each row rewrites n in [0,254)
  if (jb == 0) {
    __syncthreads();                         // drains this block's stores
    const float* __restrict__ h = ws;
    if (tid < 254) {
      float a = 0.f;
      if (tid < 127) {                       // circular wraparound region
        for (int k = tid + 1; k < NTAPS; ++k)
          a += h[k] * xrow[T_LEN + tid - k];
      } else {                               // causal with zero left-pad
        for (int k = 0; k <= tid - 127; ++k)
          a += h[k] * xrow[tid - 127 - k];
      }
      out[(size_t)row * T_LEN + tid] = a;
    }
  }
}

extern "C" void kernel_launch(void* const* d_in, const int* in_sizes, int n_in,
                              void* d_out, int out_size, void* d_ws, size_t ws_size,
                              hipStream_t stream) {
  const float* x      = (const float*)d_in[0];
  const float* w_real = (const float*)d_in[1];
  const float* w_imag = (const float*)d_in[2];
  const float* log_dt = (const float*)d_in[3];
  const float* C_real = (const float*)d_in[4];
  const float* C_imag = (const float*)d_in[5];
  const float* B_real = (const float*)d_in[6];
  const float* B_imag = (const float*)d_in[7];
  const float* Dp     = (const float*)d_in[8];
  float* out = (float*)d_out;
  float* ws  = (float*)d_ws;   // 128 f32 h + NCH*64*8 fp16 A-frags = 11.8 KB

  ssm_taps<<<1, NTAPS, 0, stream>>>(w_real, w_imag, log_dt,
                                    C_real, C_imag, B_real, B_imag, Dp, ws);
  ssm_conv<<<NROWS * BPR, BLOCK, 0, stream>>>(x, ws, out);
}